// Round 8
// baseline (2194.996 us; speedup 1.0000x reference)
//
#include <hip/hip_runtime.h>

#define JITF 1e-4f
#define LOG2PIF 1.8378770664093454f

// sizes: D=32, dy=32, M=128, N=128, B=8, T=48
// ws offsets (floats)
#define WZSM   0          // 32*4096   zs m-major: [d][m][k] (k=0..31)
#define WZS2   131072     // 32*128
#define WKINV  135168     // 32*16384  Kinv[d][i*128+j] (symmetric)
#define WA     659456     // 32*16384  A[(n*32+d)*128+m]
#define WU     1183744    // 128*32*128 U[(n*32+d)*128+m]
#define WXW    1708032    // 32*8*128  Xw[(d*8+b)*128+n]
#define WXM    1740800    // 8*32
#define WLLB   1741056    // 8
#define WKLD   1741088    // 128
#define WCNT   1741248    // int flags: d-block d at [d*16], b-block b at [(32+b)*16]
// out offsets
#define OFM 1048577
#define OFV 1060865

__device__ __forceinline__ float dot4f(const float4 a, const float4 b) {
  return fmaf(a.x, b.x, fmaf(a.y, b.y, fmaf(a.z, b.z, a.w * b.w)));
}
__device__ __forceinline__ float4 f4_fma(const float4 a, const float s, const float4 c) {
  return make_float4(fmaf(a.x,s,c.x), fmaf(a.y,s,c.y), fmaf(a.z,s,c.z), fmaf(a.w,s,c.w));
}
__device__ __forceinline__ float4 f4_axpby(const float a, const float4 x, const float b, const float4 y) {
  return make_float4(fmaf(a,x.x,b*y.x), fmaf(a,x.y,b*y.y), fmaf(a,x.z,b*y.z), fmaf(a,x.w,b*y.w));
}
__device__ __forceinline__ float aloadf(const float* p) {
  return __hip_atomic_load((float*)p, __ATOMIC_RELAXED, __HIP_MEMORY_SCOPE_AGENT);
}
__device__ __forceinline__ void astoref(float* p, float v) {
  __hip_atomic_store(p, v, __ATOMIC_RELAXED, __HIP_MEMORY_SCOPE_AGENT);
}
__device__ __forceinline__ unsigned long long aloadu(const unsigned long long* p) {
  return __hip_atomic_load((unsigned long long*)p, __ATOMIC_RELAXED, __HIP_MEMORY_SCOPE_AGENT);
}
__device__ __forceinline__ void pollge(const int* p, int target) {
  while (__hip_atomic_load((int*)p, __ATOMIC_RELAXED, __HIP_MEMORY_SCOPE_AGENT) < target)
    __builtin_amdgcn_s_sleep(1);
}
__device__ __forceinline__ void gsignal(int* p, int val, int tid) {
  __syncthreads();
  if (tid == 0) __hip_atomic_store(p, val, __ATOMIC_RELEASE, __HIP_MEMORY_SCOPE_AGENT);
}

// ---------------- Kzz build + 2-pivot in-place sweep inverse + KL partials ----------------
__global__ __launch_bounds__(512) void k_sweep(
    const float* __restrict__ ips, const float* __restrict__ ls, const float* __restrict__ osc,
    const float* __restrict__ qL, const float* __restrict__ qmu,
    float* __restrict__ zsMg, float* __restrict__ zs2g,
    float* __restrict__ Kinvg, float* __restrict__ kld, int* cnt)
{
  __shared__ float sm[22792];
  float* cur   = sm;            // [128][132]
  float* zsM   = sm + 16896;    // [128][36]
  float* rowP0 = sm + 21504;    // 132
  float* rowP1 = sm + 21636;    // 132
  float* colP0 = sm + 21768;    // 128
  float* colP1 = sm + 21896;    // 128
  float* qms   = sm + 22024;    // 128
  float* zs2   = sm + 22152;    // 128
  float* red   = sm + 22280;    // 512
  float4* cur4 = (float4*)cur;
  const float4* zsM4 = (const float4*)zsM;
  float4* rowP04 = (float4*)rowP0;
  float4* rowP14 = (float4*)rowP1;
  const int d = blockIdx.x, tid = threadIdx.x;
  const float invl = 1.0f / ls[d], oscd = osc[d];

  if (blockIdx.x == 0) { for (int l = tid; l < 640; l += 512) cnt[l] = 0; }

  for (int l = tid; l < 4096; l += 512) {
    int m = l >> 5, k = l & 31;
    zsM[m*36+k] = ips[(d*128+m)*32+k] * invl;
  }
  if (tid < 128) qms[tid] = qmu[d*128+tid];
  __syncthreads();
  if (tid < 128) {
    float s = 0.f;
#pragma unroll
    for (int kq = 0; kq < 8; kq++) { float4 v = zsM4[tid*9+kq]; s += dot4f(v, v); }
    zs2[tid] = s; zs2g[d*128+tid] = s;
  }
  for (int l = tid; l < 4096; l += 512) zsMg[d*4096+l] = zsM[(l>>5)*36 + (l&31)];
  __syncthreads();

  const int i = tid >> 2, q = tid & 3;
  {
    float4 zr[8];
#pragma unroll
    for (int kq = 0; kq < 8; kq++) zr[kq] = zsM4[i*9+kq];
    float z2i = zs2[i];
    for (int jj = 0; jj < 32; jj++) {
      int j = q*32 + jj;
      float dot = 0.f;
#pragma unroll
      for (int kq = 0; kq < 8; kq++) dot += dot4f(zr[kq], zsM4[j*9+kq]);
      float d2 = fmaxf(z2i + zs2[j] - 2.f*dot, 0.f);
      cur[i*132+j] = oscd * expf(-0.5f*d2) + (i == j ? JITF : 0.f);
    }
  }
  __syncthreads();

  float llog = 0.f;
#pragma unroll 1
  for (int kb = 0; kb < 64; kb++) {
    const int k0 = 2*kb, k1 = k0+1;
    if (tid < 33) rowP04[tid] = cur4[k0*33 + tid];
    else if (tid < 66) rowP14[tid-33] = cur4[k1*33 + (tid-33)];
    else if (tid < 194) colP0[tid-66] = cur[(tid-66)*132 + k0];
    else if (tid < 322) colP1[tid-194] = cur[(tid-194)*132 + k1];
    __syncthreads();
    const float a  = rowP0[k0];
    const float bb = rowP0[k1];
    const float c  = rowP1[k1];
    const float det = fmaf(a, c, -bb*bb);
    const float idet = 1.0f/det;
    if (tid == 0) llog += logf(det);
    const float ci0 = colP0[i], ci1 = colP1[i];
    const float w0 = (ci0*c - ci1*bb)*idet;
    const float w1 = (ci1*a - ci0*bb)*idet;
    const bool isk0 = (i == k0), isk1 = (i == k1);
    const int jqp = k0 >> 2;
    const int c0 = k0 & 3;
#pragma unroll
    for (int jj = 0; jj < 8; jj++) {
      int jq = q*8 + jj;
      float4 r0 = rowP04[jq];
      float4 r1 = rowP14[jq];
      float4 nv;
      if (isk0)      nv = f4_axpby(c*idet, r0, -bb*idet, r1);
      else if (isk1) nv = f4_axpby(-bb*idet, r0, a*idet, r1);
      else {
        nv = cur4[i*33+jq];
        nv = f4_fma(r0, -w0, nv);
        nv = f4_fma(r1, -w1, nv);
      }
      if (jq == jqp) {
        float pv0, pv1;
        if (isk0)      { pv0 = -c*idet;  pv1 =  bb*idet; }
        else if (isk1) { pv0 =  bb*idet; pv1 = -a*idet;  }
        else           { pv0 =  w0;      pv1 =  w1;      }
        if (c0 == 0) { nv.x = pv0; nv.y = pv1; }
        else         { nv.z = pv0; nv.w = pv1; }
      }
      cur4[i*33+jq] = nv;
    }
    __syncthreads();
  }
  for (int e = tid; e < 16384; e += 512) { int ii = e>>7, jj = e&127; cur[ii*132+jj] = -cur[ii*132+jj]; }
  __syncthreads();
  for (int l = tid; l < 4096; l += 512) ((float4*)(Kinvg + d*16384))[l] = cur4[(l>>5)*33 + (l&31)];

  if (tid == 0) kld[d] = 0.5f * llog;
  red[tid] = (tid < 128) ? logf(fabsf(qL[(d*128+tid)*128+tid])) : 0.f;
  __syncthreads();
  for (int s = 256; s > 0; s >>= 1) { if (tid < s) red[tid] += red[tid+s]; __syncthreads(); }
  if (tid == 0) kld[96+d] = red[0];
  __syncthreads();
  {
    float macc = 0.f;
    for (int e = tid; e < 16384; e += 512) {
      int ii = e >> 7, jj = e & 127;
      macc = fmaf(cur[ii*132+jj], qms[ii]*qms[jj], macc);
    }
    red[tid] = macc;
    __syncthreads();
    for (int s = 256; s > 0; s >>= 1) { if (tid < s) red[tid] += red[tid+s]; __syncthreads(); }
    if (tid == 0) kld[64+d] = red[0];
    __syncthreads();
  }
  {
    float tacc = 0.f;
    for (int e = tid; e < 16384; e += 512) {
      int ii = e >> 7, k2 = e & 127;
      if (k2 <= ii) {
        float w = 0.f;
        for (int m = k2; m < 128; m++) w = fmaf(cur[ii*132+m], qL[(d*128+m)*128+k2], w);
        tacc = fmaf(w, qL[(d*128+ii)*128+k2], tacc);
      }
    }
    red[tid] = tacc;
    __syncthreads();
    for (int s = 256; s > 0; s >>= 1) { if (tid < s) red[tid] += red[tid+s]; __syncthreads(); }
    if (tid == 0) kld[32+d] = red[0];
  }
}

// ---------------- U = q_mu + q_L @ eps_u ----------------
__global__ __launch_bounds__(128) void k_U(
    const float* __restrict__ qL, const float* __restrict__ qmu, const float* __restrict__ eu,
    float* __restrict__ U)
{
  __shared__ float qLs[128][129];
  __shared__ float eus[128];
  const int d = blockIdx.x >> 2, nc = blockIdx.x & 3, tid = threadIdx.x;
  for (int l = tid; l < 16384; l += 128) qLs[l >> 7][l & 127] = qL[d * 16384 + l];
  __syncthreads();
  const float qm = qmu[d * 128 + tid];
  for (int nn = 0; nn < 32; nn++) {
    int n = nc * 32 + nn;
    eus[tid] = eu[(n * 32 + d) * 128 + tid];
    __syncthreads();
    int kmax = tid + 1;
    int k4 = kmax & ~3;
    float s0 = qm, s1 = 0.f, s2 = 0.f, s3 = 0.f;
    int k = 0;
    for (; k < k4; k += 4) {
      s0 = fmaf(qLs[tid][k], eus[k], s0);
      s1 = fmaf(qLs[tid][k + 1], eus[k + 1], s1);
      s2 = fmaf(qLs[tid][k + 2], eus[k + 2], s2);
      s3 = fmaf(qLs[tid][k + 3], eus[k + 3], s3);
    }
    for (; k < kmax; k++) s0 = fmaf(qLs[tid][k], eus[k], s0);
    U[(n * 32 + d) * 128 + tid] = (s0 + s1) + (s2 + s3);
    __syncthreads();
  }
}

// ---------------- A = Kinv @ U ----------------
__global__ __launch_bounds__(256) void k_A2(
    const float* __restrict__ Kinv, const float* __restrict__ U, float* __restrict__ A)
{
  __shared__ float Kis[128][129];
  __shared__ float Us[32][129];
  const int d = blockIdx.x >> 2, nc = blockIdx.x & 3, tid = threadIdx.x;
  const int n0 = nc * 32;
  for (int l = tid; l < 16384; l += 256) Kis[l >> 7][l & 127] = Kinv[d * 16384 + l];
  for (int l = tid; l < 4096; l += 256) Us[l >> 7][l & 127] = U[((n0 + (l >> 7)) * 32 + d) * 128 + (l & 127)];
  __syncthreads();
  for (int e = tid; e < 4096; e += 256) {
    int nl = e >> 7, m = e & 127;
    float s0 = 0.f, s1 = 0.f, s2 = 0.f, s3 = 0.f;
    for (int k = 0; k < 128; k += 4) {
      s0 = fmaf(Kis[m][k], Us[nl][k], s0);
      s1 = fmaf(Kis[m][k + 1], Us[nl][k + 1], s1);
      s2 = fmaf(Kis[m][k + 2], Us[nl][k + 2], s2);
      s3 = fmaf(Kis[m][k + 3], Us[nl][k + 3], s3);
    }
    A[((n0 + nl) * 32 + d) * 128 + m] = (s0 + s1) + (s2 + s3);
  }
}

// ---------------- t = 0: full per-(n,d) GP predict ----------------
__global__ __launch_bounds__(128) void k_t0gp(
    const float* __restrict__ x0, const float* __restrict__ ls, const float* __restrict__ osc,
    const float* __restrict__ qn, const float* __restrict__ zsMg, const float* __restrict__ zs2g,
    const float* __restrict__ Kinv, const float* __restrict__ A,
    const float* __restrict__ ef, const float* __restrict__ eq, float* __restrict__ Xw)
{
  __shared__ float xqs[8*36];
  __shared__ float xq2s[8];
  __shared__ float Kxzs[8*132];
  __shared__ float T1s[8*132];
  __shared__ float covs[8][9];
  __shared__ float Lc[8][9];
  __shared__ float Arow[132];
  const float4* xqs4  = (const float4*)xqs;
  const float4* Kxzs4 = (const float4*)Kxzs;
  const float4* T1s4  = (const float4*)T1s;
  const float4* Arow4 = (const float4*)Arow;
  const int n = blockIdx.x >> 5, d = blockIdx.x & 31, tid = threadIdx.x;
  const float invl = 1.0f / ls[d], oscd = osc[d];

  float4 zr[8];
  {
    const float4* zrow = (const float4*)(zsMg + d*4096 + tid*32);
#pragma unroll
    for (int kq = 0; kq < 8; kq++) zr[kq] = zrow[kq];
  }
  const float z2m = zs2g[d*128 + tid];
  for (int l = tid; l < 256; l += 128) {
    int b = l >> 5, k = l & 31;
    xqs[b*36+k] = x0[((n*32+d)*8 + b)*32 + k] * invl;
  }
  Arow[tid] = A[(n*32+d)*128 + tid];
  __syncthreads();
  if (tid < 8) {
    float s = 0.f;
#pragma unroll
    for (int kq = 0; kq < 8; kq++) { float4 v = xqs4[tid*9+kq]; s += dot4f(v, v); }
    xq2s[tid] = s;
  }
  __syncthreads();
  {
#pragma unroll
    for (int b = 0; b < 8; b++) {
      float dot = 0.f;
#pragma unroll
      for (int kq = 0; kq < 8; kq++) dot += dot4f(zr[kq], xqs4[b*9+kq]);
      Kxzs[b*132+tid] = oscd * expf(-0.5f * fmaxf(xq2s[b] + z2m - 2.f*dot, 0.f));
    }
  }
  __syncthreads();
  {
    float a[8] = {0.f,0.f,0.f,0.f,0.f,0.f,0.f,0.f};
    const float* kp = Kinv + d*16384 + tid;
    for (int mq = 0; mq < 32; mq++) {
      float kv0 = kp[(4*mq+0)*128];
      float kv1 = kp[(4*mq+1)*128];
      float kv2 = kp[(4*mq+2)*128];
      float kv3 = kp[(4*mq+3)*128];
#pragma unroll
      for (int b = 0; b < 8; b++) {
        float4 kx = Kxzs4[b*33+mq];
        a[b] = fmaf(kx.x, kv0, fmaf(kx.y, kv1, fmaf(kx.z, kv2, fmaf(kx.w, kv3, a[b]))));
      }
    }
#pragma unroll
    for (int b = 0; b < 8; b++) T1s[b*132+tid] = a[b];
  }
  __syncthreads();
  if (tid < 64) {
    int b = tid >> 3, c = tid & 7;
    float sc = 0.f, dt = 0.f;
#pragma unroll
    for (int mq = 0; mq < 32; mq++) sc += dot4f(T1s4[b*33+mq], Kxzs4[c*33+mq]);
#pragma unroll
    for (int kq = 0; kq < 8; kq++) dt += dot4f(xqs4[b*9+kq], xqs4[c*9+kq]);
    float kxx = oscd * expf(-0.5f * fmaxf(xq2s[b] + xq2s[c] - 2.f*dt, 0.f));
    covs[b][c] = kxx - sc + (b == c ? JITF : 0.f);
  }
  __syncthreads();
  if (tid == 0) {
    for (int a = 0; a < 8; a++) {
      float s = covs[a][a];
      for (int k = 0; k < a; k++) s -= Lc[a][k]*Lc[a][k];
      float la = sqrtf(s);
      Lc[a][a] = la;
      for (int i2 = a+1; i2 < 8; i2++) {
        float s2 = covs[i2][a];
        for (int k = 0; k < a; k++) s2 -= Lc[i2][k]*Lc[a][k];
        Lc[i2][a] = s2 / la;
      }
    }
  }
  __syncthreads();
  if (tid < 8) {
    int b = tid;
    float mv = 0.f;
#pragma unroll
    for (int mq = 0; mq < 32; mq++) mv += dot4f(Kxzs4[b*33+mq], Arow4[mq]);
    float f = mv;
#pragma unroll
    for (int c = 0; c < 8; c++) if (c <= b) f = fmaf(Lc[b][c], ef[(n*32+d)*8 + c], f);
    float X = f + eq[(b*128+n)*32 + d] * sqrtf(qn[d]);
    Xw[(d*8+b)*128 + n] = X;
  }
}

// ---------------- cooperative scan: 32 d-blocks + 8 b-blocks, 1024 thr ----------------
__global__ __launch_bounds__(1024) void k_scan(
    const float* __restrict__ ls, const float* __restrict__ osc,
    const float* __restrict__ qn, const float* __restrict__ rn,
    const float* __restrict__ y,
    const float* __restrict__ ef, const float* __restrict__ eq, const float* __restrict__ er,
    const float* __restrict__ zsMg, const float* __restrict__ zs2g,
    const float* __restrict__ Kinvg, const float* __restrict__ Ag,
    float* Xw, float* xm, float* llb, const float* __restrict__ kld,
    float* out, int* cnt)
{
  __shared__ float sm[39505];
  const int blk = blockIdx.x, tid = threadIdx.x;

  if (blk < 32) {
    // ================= d-role =================
    const int d = blk;
    float* KinvS = sm;            // [128][129] 16512
    float* AT    = sm + 16512;    // [128][129] 16512  AT[m][n] = A[n][m]
    float* KxzT  = sm + 33024;    // [128][12]  1536   KxzT[m][bb]
    float* KxzS  = sm + 34560;    // [8][132]   1056
    float* T1S   = sm + 35616;    // [8][132]   1056
    float* MeanS = sm + 36672;    // [8][132]   1056
    float* xqS   = sm + 37728;    // [8][36]    288
    float* efS   = sm + 38016;    // [128][9]   1152
    float* covS  = sm + 39168;    // 81
    const float invl = 1.0f/ls[d], oscd = osc[d], qsd = sqrtf(qn[d]);
    const float4* KxzS4 = (const float4*)KxzS;
    const float4* T1S4  = (const float4*)T1S;
    const float4* xqS4  = (const float4*)xqS;
    const float4* KxzT4 = (const float4*)KxzT;
    const unsigned long long* xm_u = (const unsigned long long*)xm;

    for (int l = tid; l < 16384; l += 1024)
      KinvS[(l>>7)*129 + (l&127)] = Kinvg[d*16384 + l];
    for (int l = tid; l < 16384; l += 1024) {
      int n = l >> 7, m = l & 127;
      AT[m*129 + n] = Ag[(n*32 + d)*128 + m];
    }

    const int bb = tid >> 7, mn = tid & 127;
    float4 zr[8];
    {
      const float4* zrow = (const float4*)(zsMg + d*4096 + mn*32);
#pragma unroll
      for (int kq = 0; kq < 8; kq++) zr[kq] = zrow[kq];
    }
    const float z2m = zs2g[d*128 + mn];
    __syncthreads();

    for (int t = 1; t < 48; t++) {
      // prefetch (hidden behind the wait)
      const float v_ef = ef[((t*128 + (tid>>3))*32 + d)*8 + (tid&7)];
      const float v_eq = eq[((t*8+bb)*128 + mn)*32 + d];

      if (tid < 8) pollge(cnt + (32+tid)*16, t);
      __syncthreads();
      if (tid < 128) {
        unsigned long long u = aloadu(xm_u + tid);
        float2 f = __builtin_bit_cast(float2, u);
        int b2 = tid >> 4, k2 = (tid & 15)*2;
        xqS[b2*36 + k2]     = f.x * invl;
        xqS[b2*36 + k2 + 1] = f.y * invl;
      }
      efS[(tid>>3)*9 + (tid&7)] = v_ef;
      __syncthreads();
      { // Kxz[bb][mn] -> KxzS (row) + KxzT (transposed for bb-vectorized GEMM)
        float dot = 0.f, sq = 0.f;
#pragma unroll
        for (int kq = 0; kq < 8; kq++) {
          float4 x4 = xqS4[bb*9+kq];
          dot += dot4f(zr[kq], x4);
          sq  += dot4f(x4, x4);
        }
        float kxz = oscd * expf(-0.5f * fmaxf(sq + z2m - 2.f*dot, 0.f));
        KxzS[bb*132+mn] = kxz;
        KxzT[mn*12+bb]  = kxz;
      }
      __syncthreads();
      // fused T1 + mean GEMM, vectorized over bb (broadcast Kxz reads):
      // thread gm computes T1[0..7][gm], Mean[0..7][gm]; mm split in halves.
      float4 t1a = {0,0,0,0}, t1b = {0,0,0,0}, mea = {0,0,0,0}, meb = {0,0,0,0};
      const int gm = tid & 127;
      if (tid < 256) {
        const int mm0 = (tid >> 7) * 64;
#pragma unroll 4
        for (int it = 0; it < 64; it++) {
          const int mm = mm0 + it;
          float kv = KinvS[mm*129+gm];
          float av = AT[mm*129+gm];
          float4 kx01 = KxzT4[mm*3];
          float4 kx23 = KxzT4[mm*3+1];
          t1a = f4_fma(kx01, kv, t1a); t1b = f4_fma(kx23, kv, t1b);
          mea = f4_fma(kx01, av, mea); meb = f4_fma(kx23, av, meb);
        }
        if (tid >= 128) { // half 1 writes partials
          T1S[0*132+gm]=t1a.x; T1S[1*132+gm]=t1a.y; T1S[2*132+gm]=t1a.z; T1S[3*132+gm]=t1a.w;
          T1S[4*132+gm]=t1b.x; T1S[5*132+gm]=t1b.y; T1S[6*132+gm]=t1b.z; T1S[7*132+gm]=t1b.w;
          MeanS[0*132+gm]=mea.x; MeanS[1*132+gm]=mea.y; MeanS[2*132+gm]=mea.z; MeanS[3*132+gm]=mea.w;
          MeanS[4*132+gm]=meb.x; MeanS[5*132+gm]=meb.y; MeanS[6*132+gm]=meb.z; MeanS[7*132+gm]=meb.w;
        }
      }
      __syncthreads();
      if (tid < 128) { // half 0 accumulates
        T1S[0*132+gm]+=t1a.x; T1S[1*132+gm]+=t1a.y; T1S[2*132+gm]+=t1a.z; T1S[3*132+gm]+=t1a.w;
        T1S[4*132+gm]+=t1b.x; T1S[5*132+gm]+=t1b.y; T1S[6*132+gm]+=t1b.z; T1S[7*132+gm]+=t1b.w;
        MeanS[0*132+gm]+=mea.x; MeanS[1*132+gm]+=mea.y; MeanS[2*132+gm]+=mea.z; MeanS[3*132+gm]+=mea.w;
        MeanS[4*132+gm]+=meb.x; MeanS[5*132+gm]+=meb.y; MeanS[6*132+gm]+=meb.z; MeanS[7*132+gm]+=meb.w;
      }
      __syncthreads();
      if (tid < 64) { // cov 8x8
        int b = tid >> 3, c = tid & 7;
        float sc = 0.f, dt = 0.f, sqb = 0.f, sqc = 0.f;
#pragma unroll
        for (int mq = 0; mq < 32; mq++) sc += dot4f(T1S4[b*33+mq], KxzS4[c*33+mq]);
#pragma unroll
        for (int kq = 0; kq < 8; kq++) {
          float4 xb = xqS4[b*9+kq], xc = xqS4[c*9+kq];
          dt += dot4f(xb, xc); sqb += dot4f(xb, xb); sqc += dot4f(xc, xc);
        }
        float kxx = oscd*expf(-0.5f*fmaxf(sqb + sqc - 2.f*dt, 0.f));
        covS[b*9+c] = kxx - sc + (b==c ? JITF : 0.f);
      }
      __syncthreads();
      { // redundant per-thread chol8x8 with static-index row-bb extraction
        float Lc[8][8];
        float f = MeanS[bb*132 + mn];
#pragma unroll
        for (int a = 0; a < 8; a++) {
          float s = covS[a*9+a];
#pragma unroll
          for (int k = 0; k < 8; k++) if (k < a) s -= Lc[a][k]*Lc[a][k];
          float la = sqrtf(s);
          Lc[a][a] = la;
          if (a == bb) f = fmaf(la, efS[mn*9+a], f);
          float ila = 1.0f / la;
#pragma unroll
          for (int i2 = 0; i2 < 8; i2++) if (i2 > a) {
            float s2 = covS[i2*9+a];
#pragma unroll
            for (int k = 0; k < 8; k++) if (k < a) s2 -= Lc[i2][k]*Lc[a][k];
            float lv = s2 * ila;
            Lc[i2][a] = lv;
            if (i2 == bb) f = fmaf(lv, efS[mn*9+a], f);
          }
        }
        f = fmaf(v_eq, qsd, f);
        astoref(Xw + (d*8+bb)*128 + mn, f);
      }
      gsignal(cnt + d*16, t, tid);
    }
    if (tid < 8) pollge(cnt + (32+tid)*16, 48);
    __syncthreads();
  } else {
    // ================= b-role =================
    const int b = blk - 32;
    float* XN     = sm;          // [128][33] 4224 (centered)
    float* Ps     = sm + 4224;   // [32][36]  1152
    float* Sinvs  = sm + 5376;   // [32][33]  1056
    float* taperS = sm + 6432;   // 1024
    float* mersS  = sm + 7456;   // [48][32]  1536
    float* rowP   = sm + 8992;   // [2][4][36] 288
    float* colP   = sm + 9280;   // [2][4][36] 288
    float* detS   = sm + 9568;   // 8
    float* XmsS   = sm + 9576;   // 32
    float* residS = sm + 9608;   // 32
    float* miS    = sm + 9640;   // 32
    float* rsdS   = sm + 9672;   // 32
    float* rnS    = sm + 9704;   // 32
    const float4* er4 = (const float4*)er;
    const unsigned long long* Xw_u = (const unsigned long long*)Xw;

    if (tid < 1024) { // taper
      int ii = tid >> 5, jj = tid & 31;
      int ad = ii - jj; if (ad < 0) ad = -ad;
      int dist = (ad < 32 - ad) ? ad : (32 - ad);
      double z = (double)dist / 5.0;
      double z2 = z*z, z3 = z2*z, z4 = z3*z, z5 = z4*z;
      double gval;
      if (z < 1.0) gval = 1.0 - (5.0/3.0)*z2 + (5.0/8.0)*z3 + 0.5*z4 - 0.25*z5;
      else if (z < 2.0) gval = 4.0 - 5.0*z + (5.0/3.0)*z2 + (5.0/8.0)*z3 - 0.5*z4 + (1.0/12.0)*z5 - 2.0/(3.0*z);
      else gval = 0.0;
      taperS[tid] = (float)gval;
    }
    if (tid < 32) { rnS[tid] = rn[tid]; rsdS[tid] = sqrtf(rn[tid]); }
    if (tid < 384) { // mers for all t
      int tt = tid >> 3, jq = tid & 7;
      float sx = 0.f, sy = 0.f, sz = 0.f, sw = 0.f;
      for (int n = 0; n < 128; n++) {
        float4 e = er4[((tt*8+b)*128+n)*8 + jq];
        sx += e.x; sy += e.y; sz += e.z; sw += e.w;
      }
      int o = tt*32 + jq*4;
      mersS[o]   = sx*(1.f/128.f);
      mersS[o+1] = sy*(1.f/128.f);
      mersS[o+2] = sz*(1.f/128.f);
      mersS[o+3] = sw*(1.f/128.f);
    }
    // triangular (i<=j) mapping for the Gram phase
    int ti = -1, tj = -1;
    if (tid < 528) {
      int row = 0, rem = tid;
      while (rem >= 32 - row) { rem -= 32 - row; row++; }
      ti = row; tj = row + rem;
    }
    __syncthreads();

    float llacc = 0.f;
    const int i = tid >> 5, j = tid & 31;
    for (int t = 0; t < 48; t++) {
      float yv = 0.f;
      if (tid < 32) yv = y[(b*48+t)*32 + tid];   // prefetch
      if (t > 0) { if (tid < 32) pollge(cnt + tid*16, t); }
      __syncthreads();
      { // load Xw; shuffle row mean (within 32-lane halves); center; write XN
        unsigned long long u0 = aloadu(Xw_u + (i*8+b)*64 + j);
        unsigned long long u1 = aloadu(Xw_u + (i*8+b)*64 + j + 32);
        float2 f0 = __builtin_bit_cast(float2, u0);
        float2 f1 = __builtin_bit_cast(float2, u1);
        float s4 = (f0.x+f0.y)+(f1.x+f1.y);
#pragma unroll
        for (int mk = 1; mk <= 16; mk <<= 1) s4 += __shfl_xor(s4, mk, 64);
        float mu = s4 * (1.f/128.f);
        if (j == 0) XmsS[i] = mu;
        XN[(2*j)*33+i]    = f0.x - mu;
        XN[(2*j+1)*33+i]  = f0.y - mu;
        XN[(2*j+64)*33+i] = f1.x - mu;
        XN[(2*j+65)*33+i] = f1.y - mu;
      }
      __syncthreads();
      if (tid < 528) { // P upper-triangle (scalar, conflict-free) + mirror
        float a0 = 0.f, a1 = 0.f;
#pragma unroll 4
        for (int n = 0; n < 128; n += 2) {
          a0 = fmaf(XN[n*33+ti],     XN[n*33+tj],     a0);
          a1 = fmaf(XN[(n+1)*33+ti], XN[(n+1)*33+tj], a1);
        }
        float pv = taperS[ti*32+tj] * (a0+a1) * (1.f/127.f);
        Ps[ti*36+tj] = pv;
        Ps[tj*36+ti] = pv;
      }
      __syncthreads();
      float val = Ps[i*36+j] + ((i==j) ? rnS[i] : 0.f);
      // 4x4-pivot block sweep of S -> val = (-Sinv)[i][j], 8 barriers
#pragma unroll 1
      for (int kb = 0; kb < 8; kb++) {
        const int k0 = kb*4;
        float* rowPb = rowP + (kb&1)*144;
        float* colPb = colP + (kb&1)*144;
        if (i >= k0 && i < k0+4) rowPb[(i-k0)*36 + j] = val;
        if (j >= k0 && j < k0+4) colPb[(j-k0)*36 + i] = val;
        __syncthreads();
        float p00 = rowPb[0*36+k0+0], p01 = rowPb[0*36+k0+1], p02 = rowPb[0*36+k0+2], p03 = rowPb[0*36+k0+3];
        float p11 = rowPb[1*36+k0+1], p12 = rowPb[1*36+k0+2], p13 = rowPb[1*36+k0+3];
        float p22 = rowPb[2*36+k0+2], p23 = rowPb[2*36+k0+3], p33 = rowPb[3*36+k0+3];
        float deta = fmaf(p00, p11, -p01*p01);
        float ia = 1.0f/deta;
        float ai00 = p11*ia, ai01 = -p01*ia, ai11 = p00*ia;
        float m00 = ai00*p02 + ai01*p12;
        float m01 = ai00*p03 + ai01*p13;
        float m10 = ai01*p02 + ai11*p12;
        float m11 = ai01*p03 + ai11*p13;
        float s00 = p22 - (p02*m00 + p12*m10);
        float s01 = p23 - (p02*m01 + p12*m11);
        float s11 = p33 - (p03*m01 + p13*m11);
        float dets = fmaf(s00, s11, -s01*s01);
        float is = 1.0f/dets;
        float si00 = s11*is, si01 = -s01*is, si11 = s00*is;
        float n00 = m00*si00 + m01*si01;
        float n01 = m00*si01 + m01*si11;
        float n10 = m10*si00 + m11*si01;
        float n11 = m10*si01 + m11*si11;
        float q00 = ai00 + n00*m00 + n01*m01;
        float q01 = ai01 + n00*m10 + n01*m11;
        float q11 = ai11 + n10*m10 + n11*m11;
        const float PI[4][4] = {
          {  q00,  q01, -n00, -n01 },
          {  q01,  q11, -n10, -n11 },
          { -n00, -n10, si00, si01 },
          { -n01, -n11, si01, si11 }
        };
        if (tid == 0) detS[kb] = deta * dets;
        float cI[4], rJ[4];
#pragma unroll
        for (int a = 0; a < 4; a++) { cI[a] = colPb[a*36 + i]; rJ[a] = rowPb[a*36 + j]; }
        float w[4];
#pragma unroll
        for (int bq = 0; bq < 4; bq++)
          w[bq] = cI[0]*PI[0][bq] + cI[1]*PI[1][bq] + cI[2]*PI[2][bq] + cI[3]*PI[3][bq];
        float interior = val - (w[0]*rJ[0] + w[1]*rJ[1] + w[2]*rJ[2] + w[3]*rJ[3]);
        const int r = i - k0, c = j - k0;
        const bool ip = (r >= 0 && r < 4), jp = (c >= 0 && c < 4);
        float pr[4], pc[4];
#pragma unroll
        for (int bq = 0; bq < 4; bq++) {
          pr[bq] = (r==0) ? PI[0][bq] : (r==1) ? PI[1][bq] : (r==2) ? PI[2][bq] : PI[3][bq];
          pc[bq] = (c==0) ? PI[bq][0] : (c==1) ? PI[bq][1] : (c==2) ? PI[bq][2] : PI[bq][3];
        }
        float rowv = pr[0]*rJ[0] + pr[1]*rJ[1] + pr[2]*rJ[2] + pr[3]*rJ[3];
        float colv = cI[0]*pc[0] + cI[1]*pc[1] + cI[2]*pc[2] + cI[3]*pc[3];
        float prc  = (c==0) ? pr[0] : (c==1) ? pr[1] : (c==2) ? pr[2] : pr[3];
        float nv = interior;
        if (ip) nv = rowv;
        if (jp) nv = colv;
        if (ip && jp) nv = -prc;
        val = nv;
      }
      Sinvs[i*33+j] = -val;
      if (tid < 32) {
        float rs = yv - XmsS[tid];
        residS[tid] = rs;
        miS[tid] = fmaf(mersS[t*32+tid], rsdS[tid], rs);
      }
      __syncthreads();
      if (tid < 32) {
        // beta = Sinv@mi; xmp = Xms + mi - rn*beta ; var = rn - rn^2*Sinv_ii  (H = I)
        float bt = 0.f;
#pragma unroll
        for (int k = 0; k < 32; k++) bt = fmaf(Sinvs[tid*33+k], miS[k], bt);
        float xmp = XmsS[tid] + miS[tid] - rnS[tid]*bt;
        out[OFM + (b*48+t)*32 + tid] = xmp;
        out[OFV + (b*48+t)*32 + tid] = rnS[tid] - rnS[tid]*rnS[tid]*Sinvs[tid*33+tid];
        astoref(xm + b*32 + tid, xmp);
      } else if (tid < 64) {
        int ii = tid - 32;
        float al = 0.f;
#pragma unroll
        for (int k = 0; k < 32; k++) al = fmaf(Sinvs[ii*33+k], residS[k], al);
        float contrib = al * residS[ii] + ((ii < 8) ? logf(detS[ii]) : 0.f);
#pragma unroll
        for (int mk = 1; mk <= 16; mk <<= 1) contrib += __shfl_xor(contrib, mk, 64);
        if (ii == 0) {
          llacc += -0.5f*(32.f*LOG2PIF + contrib);
          if (t == 47) astoref(llb + b, llacc);
        }
      }
      gsignal(cnt + (32+b)*16, t+1, tid);
    }
    if (tid < 8) pollge(cnt + (32+tid)*16, 48);
    __syncthreads();
  }

  // ---------------- epilogue: x_final broadcast + elbo ----------------
  if (tid < 128) {
    unsigned long long u = aloadu((const unsigned long long*)xm + tid);
    float2 f = __builtin_bit_cast(float2, u);
    sm[2*tid] = f.x; sm[2*tid+1] = f.y;
  }
  __syncthreads();
  for (int v = blk*1024 + tid; v < 1048576; v += 40960)
    out[1 + v] = sm[v & 255];
  if (blk == 32 && tid == 0) {
    double ll = 0.0;
    for (int i2 = 0; i2 < 8; i2++) ll += (double)aloadf(llb + i2);
    double ldK = 0.0, tr = 0.0, mah = 0.0, ldS = 0.0;
    for (int d2 = 0; d2 < 32; d2++) {
      ldK += (double)kld[d2];
      tr  += (double)kld[32+d2];
      mah += (double)kld[64+d2];
      ldS += (double)kld[96+d2];
    }
    double klv = 0.5*(tr + mah - 4096.0 + 2.0*ldK - 2.0*ldS);
    out[0] = (float)(ll - klv/100000.0);
  }
}

extern "C" void kernel_launch(void* const* d_in, const int* in_sizes, int n_in,
                              void* d_out, int out_size, void* d_ws, size_t ws_size,
                              hipStream_t stream) {
  const float* ips = (const float*)d_in[0];
  const float* ls  = (const float*)d_in[2];
  const float* osc = (const float*)d_in[3];
  const float* qmu = (const float*)d_in[4];
  const float* qL  = (const float*)d_in[5];
  const float* qn  = (const float*)d_in[6];
  const float* rn  = (const float*)d_in[7];
  const float* x0  = (const float*)d_in[8];
  const float* y   = (const float*)d_in[9];
  const float* eu  = (const float*)d_in[10];
  const float* ef  = (const float*)d_in[11];
  const float* eq  = (const float*)d_in[12];
  const float* er  = (const float*)d_in[13];
  float* out = (float*)d_out;
  float* ws  = (float*)d_ws;

  float* w_zsm  = ws + WZSM;
  float* w_zs2  = ws + WZS2;
  float* w_kinv = ws + WKINV;
  float* w_A    = ws + WA;
  float* w_U    = ws + WU;
  float* w_Xw   = ws + WXW;
  float* w_xm   = ws + WXM;
  float* w_llb  = ws + WLLB;
  float* w_kld  = ws + WKLD;
  int*   w_cnt  = (int*)(ws + WCNT);

  k_sweep<<<32, 512, 0, stream>>>(ips, ls, osc, qL, qmu, w_zsm, w_zs2, w_kinv, w_kld, w_cnt);
  k_U<<<128, 128, 0, stream>>>(qL, qmu, eu, w_U);
  k_A2<<<128, 256, 0, stream>>>(w_kinv, w_U, w_A);
  k_t0gp<<<4096, 128, 0, stream>>>(x0, ls, osc, qn, w_zsm, w_zs2, w_kinv, w_A, ef, eq, w_Xw);
  void* args[] = { (void*)&ls, (void*)&osc, (void*)&qn, (void*)&rn, (void*)&y,
                   (void*)&ef, (void*)&eq, (void*)&er, (void*)&w_zsm, (void*)&w_zs2,
                   (void*)&w_kinv, (void*)&w_A, (void*)&w_Xw, (void*)&w_xm, (void*)&w_llb,
                   (void*)&w_kld, (void*)&out, (void*)&w_cnt };
  hipLaunchCooperativeKernel((void*)k_scan, dim3(40), dim3(1024), args, 0, stream);
}

// Round 9
// 1624.977 us; speedup vs baseline: 1.3508x; 1.3508x over previous
//
#include <hip/hip_runtime.h>

#define JITF 1e-4f
#define LOG2PIF 1.8378770664093454f

// sizes: D=32, dy=32, M=128, N=128, B=8, T=48
// ws offsets (floats)
#define WZSM   0          // 32*4096   zs m-major: [d][m][k] (k=0..31)
#define WZS2   131072     // 32*128
#define WKINV  135168     // 32*16384  Kinv[d][i*128+j] (symmetric)
#define WA     659456     // 32*16384  A[(n*32+d)*128+m]
#define WXW    1708032    // 32*8*128  Xw[(d*8+b)*128+n]
#define WXM    1740800    // 8*32
#define WLLB   1741056    // 8
#define WKLD   1741088    // 128
#define WCNT   1741248    // int flags: d-block d at [d*16], b-block b at [(32+b)*16]
// out offsets
#define OFM 1048577
#define OFV 1060865

__device__ __forceinline__ float dot4f(const float4 a, const float4 b) {
  return fmaf(a.x, b.x, fmaf(a.y, b.y, fmaf(a.z, b.z, a.w * b.w)));
}
__device__ __forceinline__ float4 f4_fma(const float4 a, const float s, const float4 c) {
  return make_float4(fmaf(a.x,s,c.x), fmaf(a.y,s,c.y), fmaf(a.z,s,c.z), fmaf(a.w,s,c.w));
}
__device__ __forceinline__ float4 f4_axpby(const float a, const float4 x, const float b, const float4 y) {
  return make_float4(fmaf(a,x.x,b*y.x), fmaf(a,x.y,b*y.y), fmaf(a,x.z,b*y.z), fmaf(a,x.w,b*y.w));
}
__device__ __forceinline__ float aloadf(const float* p) {
  return __hip_atomic_load((float*)p, __ATOMIC_RELAXED, __HIP_MEMORY_SCOPE_AGENT);
}
__device__ __forceinline__ void astoref(float* p, float v) {
  __hip_atomic_store(p, v, __ATOMIC_RELAXED, __HIP_MEMORY_SCOPE_AGENT);
}
__device__ __forceinline__ unsigned long long aloadu(const unsigned long long* p) {
  return __hip_atomic_load((unsigned long long*)p, __ATOMIC_RELAXED, __HIP_MEMORY_SCOPE_AGENT);
}
__device__ __forceinline__ void pollge(const int* p, int target) {
  while (__hip_atomic_load((int*)p, __ATOMIC_RELAXED, __HIP_MEMORY_SCOPE_AGENT) < target)
    __builtin_amdgcn_s_sleep(1);
}
__device__ __forceinline__ void gsignal(int* p, int val, int tid) {
  __syncthreads();
  if (tid == 0) __hip_atomic_store(p, val, __ATOMIC_RELEASE, __HIP_MEMORY_SCOPE_AGENT);
}

// ---------------- Kzz build + 2-pivot in-place sweep inverse + KL partials (1024 thr) ----------------
__global__ __launch_bounds__(1024) void k_sweep(
    const float* __restrict__ ips, const float* __restrict__ ls, const float* __restrict__ osc,
    const float* __restrict__ qL, const float* __restrict__ qmu,
    float* __restrict__ zsMg, float* __restrict__ zs2g,
    float* __restrict__ Kinvg, float* __restrict__ kld, int* cnt)
{
  __shared__ float sm[40200];
  float* cur   = sm;            // [128][132] 16896
  float* qLs   = sm + 16896;    // [128][132] 16896
  float* zsM   = sm + 33792;    // [128][36]  4608
  float* rowP0 = sm + 38400;    // 132
  float* rowP1 = sm + 38532;    // 132
  float* colP0 = sm + 38664;    // 128
  float* colP1 = sm + 38792;    // 128
  float* qms   = sm + 38920;    // 128
  float* zs2   = sm + 39048;    // 128
  float* red   = sm + 39176;    // 1024
  float4* cur4 = (float4*)cur;
  const float4* zsM4 = (const float4*)zsM;
  float4* rowP04 = (float4*)rowP0;
  float4* rowP14 = (float4*)rowP1;
  const int d = blockIdx.x, tid = threadIdx.x;
  const float invl = 1.0f / ls[d], oscd = osc[d];

  if (blockIdx.x == 0) { for (int l = tid; l < 640; l += 1024) cnt[l] = 0; }

  for (int l = tid; l < 4096; l += 1024) {
    int m = l >> 5, k = l & 31;
    zsM[m*36+k] = ips[(d*128+m)*32+k] * invl;
  }
  for (int l = tid; l < 16384; l += 1024)
    qLs[(l>>7)*132 + (l&127)] = qL[d*16384 + l];
  if (tid < 128) qms[tid] = qmu[d*128+tid];
  __syncthreads();
  if (tid < 128) {
    float s = 0.f;
#pragma unroll
    for (int kq = 0; kq < 8; kq++) { float4 v = zsM4[tid*9+kq]; s += dot4f(v, v); }
    zs2[tid] = s; zs2g[d*128+tid] = s;
  }
  for (int l = tid; l < 4096; l += 1024) zsMg[d*4096+l] = zsM[(l>>5)*36 + (l&31)];
  __syncthreads();

  const int i = tid >> 3, q = tid & 7;
  { // Kzz build: thread = (row i, 16-col chunk q)
    float4 zr[8];
#pragma unroll
    for (int kq = 0; kq < 8; kq++) zr[kq] = zsM4[i*9+kq];
    float z2i = zs2[i];
    for (int jj = 0; jj < 16; jj++) {
      int j = q*16 + jj;
      float dot = 0.f;
#pragma unroll
      for (int kq = 0; kq < 8; kq++) dot += dot4f(zr[kq], zsM4[j*9+kq]);
      float d2 = fmaxf(z2i + zs2[j] - 2.f*dot, 0.f);
      cur[i*132+j] = oscd * expf(-0.5f*d2) + (i == j ? JITF : 0.f);
    }
  }
  __syncthreads();

  // 64 2-pivot in-place block-sweep steps -> cur = -Kzz^-1
  float llog = 0.f;
#pragma unroll 1
  for (int kb = 0; kb < 64; kb++) {
    const int k0 = 2*kb, k1 = k0+1;
    if (tid < 33) rowP04[tid] = cur4[k0*33 + tid];
    else if (tid < 66) rowP14[tid-33] = cur4[k1*33 + (tid-33)];
    else if (tid < 194) colP0[tid-66] = cur[(tid-66)*132 + k0];
    else if (tid < 322) colP1[tid-194] = cur[(tid-194)*132 + k1];
    __syncthreads();
    const float a  = rowP0[k0];
    const float bb = rowP0[k1];
    const float c  = rowP1[k1];
    const float det = fmaf(a, c, -bb*bb);
    const float idet = 1.0f/det;
    if (tid == 0) llog += logf(det);
    const float ci0 = colP0[i], ci1 = colP1[i];
    const float w0 = (ci0*c - ci1*bb)*idet;
    const float w1 = (ci1*a - ci0*bb)*idet;
    const bool isk0 = (i == k0), isk1 = (i == k1);
    const int jqp = k0 >> 2;
    const int c0 = k0 & 3;
    auto body = [&](int jq) {
      float4 r0 = rowP04[jq];
      float4 r1 = rowP14[jq];
      float4 nv;
      if (isk0)      nv = f4_axpby(c*idet, r0, -bb*idet, r1);
      else if (isk1) nv = f4_axpby(-bb*idet, r0, a*idet, r1);
      else {
        nv = cur4[i*33+jq];
        nv = f4_fma(r0, -w0, nv);
        nv = f4_fma(r1, -w1, nv);
      }
      if (jq == jqp) {
        float pv0, pv1;
        if (isk0)      { pv0 = -c*idet;  pv1 =  bb*idet; }
        else if (isk1) { pv0 =  bb*idet; pv1 = -a*idet;  }
        else           { pv0 =  w0;      pv1 =  w1;      }
        if (c0 == 0) { nv.x = pv0; nv.y = pv1; }
        else         { nv.z = pv0; nv.w = pv1; }
      }
      cur4[i*33+jq] = nv;
    };
#pragma unroll
    for (int jj = 0; jj < 4; jj++) body(q*4 + jj);
    if (q == 7) body(32);
    __syncthreads();
  }
  for (int e = tid; e < 16384; e += 1024) { int ii = e>>7, jj = e&127; cur[ii*132+jj] = -cur[ii*132+jj]; }
  __syncthreads();
  for (int l = tid; l < 4096; l += 1024) ((float4*)(Kinvg + d*16384))[l] = cur4[(l>>5)*33 + (l&31)];

  if (tid == 0) kld[d] = 0.5f * llog;
  red[tid] = (tid < 128) ? logf(fabsf(qLs[tid*132+tid])) : 0.f;
  __syncthreads();
  for (int s = 512; s > 0; s >>= 1) { if (tid < s) red[tid] += red[tid+s]; __syncthreads(); }
  if (tid == 0) kld[96+d] = red[0];
  __syncthreads();
  { // mah = qmu^T Kinv qmu
    float macc = 0.f;
    for (int e = tid; e < 16384; e += 1024) {
      int ii = e >> 7, jj = e & 127;
      macc = fmaf(cur[ii*132+jj], qms[ii]*qms[jj], macc);
    }
    red[tid] = macc;
    __syncthreads();
    for (int s = 512; s > 0; s >>= 1) { if (tid < s) red[tid] += red[tid+s]; __syncthreads(); }
    if (tid == 0) kld[64+d] = red[0];
    __syncthreads();
  }
  { // trace = sum_{i,k} qL[i][k]*(Kinv qL)[i][k]   (qL from LDS)
    float tacc = 0.f;
    for (int e = tid; e < 16384; e += 1024) {
      int ii = e >> 7, k2 = e & 127;
      if (k2 <= ii) {
        float w = 0.f;
        for (int m = k2; m < 128; m++) w = fmaf(cur[ii*132+m], qLs[m*132+k2], w);
        tacc = fmaf(w, qLs[ii*132+k2], tacc);
      }
    }
    red[tid] = tacc;
    __syncthreads();
    for (int s = 512; s > 0; s >>= 1) { if (tid < s) red[tid] += red[tid+s]; __syncthreads(); }
    if (tid == 0) kld[32+d] = red[0];
  }
}

// ---------------- fused U = qmu + qL@eps_u ; A = Kinv@U ----------------
__global__ __launch_bounds__(256) void k_UA(
    const float* __restrict__ qL, const float* __restrict__ qmu, const float* __restrict__ eu,
    const float* __restrict__ Kinv, float* __restrict__ A)
{
  __shared__ float big[16512];   // [128][129]: qL, then Kinv
  __shared__ float Us[4128];     // [32][129]
  __shared__ float eus[4128];    // [32][129]
  const int d = blockIdx.x >> 2, nc = blockIdx.x & 3, tid = threadIdx.x;
  const int n0 = nc * 32;
  for (int l = tid; l < 16384; l += 256) big[(l>>7)*129 + (l&127)] = qL[d*16384 + l];
  for (int l = tid; l < 4096; l += 256)
    eus[(l>>7)*129 + (l&127)] = eu[((n0 + (l>>7))*32 + d)*128 + (l&127)];
  __syncthreads();
  for (int e = tid; e < 4096; e += 256) {
    int nl = e >> 7, m = e & 127;
    float s0 = qmu[d*128 + m], s1 = 0.f, s2 = 0.f, s3 = 0.f;
    int kmax = m + 1, k4 = kmax & ~3, k = 0;
    for (; k < k4; k += 4) {
      s0 = fmaf(big[m*129+k],   eus[nl*129+k],   s0);
      s1 = fmaf(big[m*129+k+1], eus[nl*129+k+1], s1);
      s2 = fmaf(big[m*129+k+2], eus[nl*129+k+2], s2);
      s3 = fmaf(big[m*129+k+3], eus[nl*129+k+3], s3);
    }
    for (; k < kmax; k++) s0 = fmaf(big[m*129+k], eus[nl*129+k], s0);
    Us[nl*129+m] = (s0+s1)+(s2+s3);
  }
  __syncthreads();
  for (int l = tid; l < 16384; l += 256) big[(l>>7)*129 + (l&127)] = Kinv[d*16384 + l];
  __syncthreads();
  for (int e = tid; e < 4096; e += 256) {
    int nl = e >> 7, m = e & 127;
    float s0 = 0.f, s1 = 0.f, s2 = 0.f, s3 = 0.f;
    for (int k = 0; k < 128; k += 4) {
      s0 = fmaf(big[m*129+k],   Us[nl*129+k],   s0);
      s1 = fmaf(big[m*129+k+1], Us[nl*129+k+1], s1);
      s2 = fmaf(big[m*129+k+2], Us[nl*129+k+2], s2);
      s3 = fmaf(big[m*129+k+3], Us[nl*129+k+3], s3);
    }
    A[((n0+nl)*32 + d)*128 + m] = (s0+s1)+(s2+s3);
  }
}

// ---------------- t = 0: full per-(n,d) GP predict ----------------
__global__ __launch_bounds__(128) void k_t0gp(
    const float* __restrict__ x0, const float* __restrict__ ls, const float* __restrict__ osc,
    const float* __restrict__ qn, const float* __restrict__ zsMg, const float* __restrict__ zs2g,
    const float* __restrict__ Kinv, const float* __restrict__ A,
    const float* __restrict__ ef, const float* __restrict__ eq, float* __restrict__ Xw)
{
  __shared__ float xqs[8*36];
  __shared__ float xq2s[8];
  __shared__ float Kxzs[8*132];
  __shared__ float T1s[8*132];
  __shared__ float covs[8][9];
  __shared__ float Lc[8][9];
  __shared__ float Arow[132];
  const float4* xqs4  = (const float4*)xqs;
  const float4* Kxzs4 = (const float4*)Kxzs;
  const float4* T1s4  = (const float4*)T1s;
  const float4* Arow4 = (const float4*)Arow;
  const int n = blockIdx.x >> 5, d = blockIdx.x & 31, tid = threadIdx.x;
  const float invl = 1.0f / ls[d], oscd = osc[d];

  float4 zr[8];
  {
    const float4* zrow = (const float4*)(zsMg + d*4096 + tid*32);
#pragma unroll
    for (int kq = 0; kq < 8; kq++) zr[kq] = zrow[kq];
  }
  const float z2m = zs2g[d*128 + tid];
  for (int l = tid; l < 256; l += 128) {
    int b = l >> 5, k = l & 31;
    xqs[b*36+k] = x0[((n*32+d)*8 + b)*32 + k] * invl;
  }
  Arow[tid] = A[(n*32+d)*128 + tid];
  __syncthreads();
  if (tid < 8) {
    float s = 0.f;
#pragma unroll
    for (int kq = 0; kq < 8; kq++) { float4 v = xqs4[tid*9+kq]; s += dot4f(v, v); }
    xq2s[tid] = s;
  }
  __syncthreads();
  {
#pragma unroll
    for (int b = 0; b < 8; b++) {
      float dot = 0.f;
#pragma unroll
      for (int kq = 0; kq < 8; kq++) dot += dot4f(zr[kq], xqs4[b*9+kq]);
      Kxzs[b*132+tid] = oscd * expf(-0.5f * fmaxf(xq2s[b] + z2m - 2.f*dot, 0.f));
    }
  }
  __syncthreads();
  {
    float a[8] = {0.f,0.f,0.f,0.f,0.f,0.f,0.f,0.f};
    const float* kp = Kinv + d*16384 + tid;
    for (int mq = 0; mq < 32; mq++) {
      float kv0 = kp[(4*mq+0)*128];
      float kv1 = kp[(4*mq+1)*128];
      float kv2 = kp[(4*mq+2)*128];
      float kv3 = kp[(4*mq+3)*128];
#pragma unroll
      for (int b = 0; b < 8; b++) {
        float4 kx = Kxzs4[b*33+mq];
        a[b] = fmaf(kx.x, kv0, fmaf(kx.y, kv1, fmaf(kx.z, kv2, fmaf(kx.w, kv3, a[b]))));
      }
    }
#pragma unroll
    for (int b = 0; b < 8; b++) T1s[b*132+tid] = a[b];
  }
  __syncthreads();
  if (tid < 64) {
    int b = tid >> 3, c = tid & 7;
    float sc = 0.f, dt = 0.f;
#pragma unroll
    for (int mq = 0; mq < 32; mq++) sc += dot4f(T1s4[b*33+mq], Kxzs4[c*33+mq]);
#pragma unroll
    for (int kq = 0; kq < 8; kq++) dt += dot4f(xqs4[b*9+kq], xqs4[c*9+kq]);
    float kxx = oscd * expf(-0.5f * fmaxf(xq2s[b] + xq2s[c] - 2.f*dt, 0.f));
    covs[b][c] = kxx - sc + (b == c ? JITF : 0.f);
  }
  __syncthreads();
  if (tid == 0) {
    for (int a = 0; a < 8; a++) {
      float s = covs[a][a];
      for (int k = 0; k < a; k++) s -= Lc[a][k]*Lc[a][k];
      float la = sqrtf(s);
      Lc[a][a] = la;
      for (int i2 = a+1; i2 < 8; i2++) {
        float s2 = covs[i2][a];
        for (int k = 0; k < a; k++) s2 -= Lc[i2][k]*Lc[a][k];
        Lc[i2][a] = s2 / la;
      }
    }
  }
  __syncthreads();
  if (tid < 8) {
    int b = tid;
    float mv = 0.f;
#pragma unroll
    for (int mq = 0; mq < 32; mq++) mv += dot4f(Kxzs4[b*33+mq], Arow4[mq]);
    float f = mv;
#pragma unroll
    for (int c = 0; c < 8; c++) if (c <= b) f = fmaf(Lc[b][c], ef[(n*32+d)*8 + c], f);
    float X = f + eq[(b*128+n)*32 + d] * sqrtf(qn[d]);
    Xw[(d*8+b)*128 + n] = X;
  }
}

// ---------------- cooperative scan: 32 d-blocks + 8 b-blocks, 1024 thr (R6-proven) ----------------
__global__ __launch_bounds__(1024) void k_scan(
    const float* __restrict__ ls, const float* __restrict__ osc,
    const float* __restrict__ qn, const float* __restrict__ rn,
    const float* __restrict__ y,
    const float* __restrict__ ef, const float* __restrict__ eq, const float* __restrict__ er,
    const float* __restrict__ zsMg, const float* __restrict__ zs2g,
    const float* __restrict__ Kinvg, const float* __restrict__ Ag,
    float* Xw, float* xm, float* llb, const float* __restrict__ kld,
    float* out, int* cnt)
{
  __shared__ float sm[36704];
  const int blk = blockIdx.x, tid = threadIdx.x;

  if (blk < 32) {
    // ================= d-role =================
    const int d = blk;
    float* KinvS = sm;           // [128][129] 16512
    float* AT    = sm + 16512;   // [128][129] 16512  (AT[m][n] = A[n][m])
    float* KxzS  = sm + 33024;   // [8][132]   1056
    float* T1S   = sm + 34080;   // [8][132]   1056
    float* xqS   = sm + 35136;   // [8][36]    288
    float* efS   = sm + 35424;   // [128][9]   1152
    float* covS  = sm + 36576;   // 81
    const float invl = 1.0f/ls[d], oscd = osc[d], qsd = sqrtf(qn[d]);
    const float4* KxzS4 = (const float4*)KxzS;
    const float4* T1S4  = (const float4*)T1S;
    const float4* xqS4  = (const float4*)xqS;
    const unsigned long long* xm_u = (const unsigned long long*)xm;

    for (int l = tid; l < 16384; l += 1024)
      KinvS[(l>>7)*129 + (l&127)] = Kinvg[d*16384 + l];
    for (int l = tid; l < 16384; l += 1024) {
      int n = l >> 7, m = l & 127;
      AT[m*129 + n] = Ag[(n*32 + d)*128 + m];
    }

    const int bb = tid >> 7, mn = tid & 127;
    float4 zr[8];
    {
      const float4* zrow = (const float4*)(zsMg + d*4096 + mn*32);
#pragma unroll
      for (int kq = 0; kq < 8; kq++) zr[kq] = zrow[kq];
    }
    const float z2m = zs2g[d*128 + mn];
    __syncthreads();

    for (int t = 1; t < 48; t++) {
      // prefetch (hidden behind the wait)
      const float v_ef = ef[((t*128 + (tid>>3))*32 + d)*8 + (tid&7)];
      const float v_eq = eq[((t*8+bb)*128 + mn)*32 + d];

      if (tid < 8) pollge(cnt + (32+tid)*16, t);
      __syncthreads();
      if (tid < 128) {
        unsigned long long u = aloadu(xm_u + tid);
        float2 f = __builtin_bit_cast(float2, u);
        int b2 = tid >> 4, k2 = (tid & 15)*2;
        xqS[b2*36 + k2]     = f.x * invl;
        xqS[b2*36 + k2 + 1] = f.y * invl;
      }
      efS[(tid>>3)*9 + (tid&7)] = v_ef;
      __syncthreads();
      { // Kxz[bb][mn]
        float dot = 0.f, sq = 0.f;
#pragma unroll
        for (int kq = 0; kq < 8; kq++) {
          float4 x4 = xqS4[bb*9+kq];
          dot += dot4f(zr[kq], x4);
          sq  += dot4f(x4, x4);
        }
        KxzS[bb*132+mn] = oscd * expf(-0.5f * fmaxf(sq + z2m - 2.f*dot, 0.f));
      }
      __syncthreads();
      float mv;
      { // fused T1[bb][mn] + mean[bb][mn] (both LDS, conflict-free)
        float t1a = 0.f, t1b = 0.f, ma = 0.f, mb2 = 0.f;
#pragma unroll 8
        for (int mm = 0; mm < 128; mm += 2) {
          float kx0 = KxzS[bb*132+mm], kx1 = KxzS[bb*132+mm+1];
          t1a = fmaf(kx0, KinvS[mm*129+mn],     t1a);
          t1b = fmaf(kx1, KinvS[(mm+1)*129+mn], t1b);
          ma  = fmaf(kx0, AT[mm*129+mn],        ma);
          mb2 = fmaf(kx1, AT[(mm+1)*129+mn],    mb2);
        }
        T1S[bb*132+mn] = t1a + t1b;
        mv = ma + mb2;
      }
      __syncthreads();
      if (tid < 64) { // cov 8x8
        int b = tid >> 3, c = tid & 7;
        float sc = 0.f, dt = 0.f, sqb = 0.f, sqc = 0.f;
#pragma unroll
        for (int mq = 0; mq < 32; mq++) sc += dot4f(T1S4[b*33+mq], KxzS4[c*33+mq]);
#pragma unroll
        for (int kq = 0; kq < 8; kq++) {
          float4 xb = xqS4[b*9+kq], xc = xqS4[c*9+kq];
          dt += dot4f(xb, xc); sqb += dot4f(xb, xb); sqc += dot4f(xc, xc);
        }
        float kxx = oscd*expf(-0.5f*fmaxf(sqb + sqc - 2.f*dt, 0.f));
        covS[b*9+c] = kxx - sc + (b==c ? JITF : 0.f);
      }
      __syncthreads();
      { // redundant per-thread chol8x8 with static-index row-bb extraction
        float Lc[8][8];
        float f = mv;
#pragma unroll
        for (int a = 0; a < 8; a++) {
          float s = covS[a*9+a];
#pragma unroll
          for (int k = 0; k < 8; k++) if (k < a) s -= Lc[a][k]*Lc[a][k];
          float la = sqrtf(s);
          Lc[a][a] = la;
          if (a == bb) f = fmaf(la, efS[mn*9+a], f);
          float ila = 1.0f / la;
#pragma unroll
          for (int i2 = 0; i2 < 8; i2++) if (i2 > a) {
            float s2 = covS[i2*9+a];
#pragma unroll
            for (int k = 0; k < 8; k++) if (k < a) s2 -= Lc[i2][k]*Lc[a][k];
            float lv = s2 * ila;
            Lc[i2][a] = lv;
            if (i2 == bb) f = fmaf(lv, efS[mn*9+a], f);
          }
        }
        f = fmaf(v_eq, qsd, f);
        astoref(Xw + (d*8+bb)*128 + mn, f);
      }
      gsignal(cnt + d*16, t, tid);
    }
    if (tid < 8) pollge(cnt + (32+tid)*16, 48);
    __syncthreads();
  } else {
    // ================= b-role =================
    const int b = blk - 32;
    float* XN     = sm;          // [128][33] 4224 (centered)
    float* Ps     = sm + 4224;   // [32][36]  1152
    float* Sinvs  = sm + 5376;   // [32][33]  1056
    float* taperS = sm + 6432;   // 1024
    float* mersS  = sm + 7456;   // [48][32]  1536
    float* rowP   = sm + 8992;   // [2][2][36] 144
    float* colP   = sm + 9136;   // 144
    float* detS   = sm + 9280;   // 16
    float* XmsS   = sm + 9296;   // 32
    float* residS = sm + 9328;   // 32
    float* miS    = sm + 9360;   // 32
    float* rsdS   = sm + 9392;   // 32
    float* rnS    = sm + 9424;   // 32
    const float4* er4 = (const float4*)er;
    const unsigned long long* Xw_u = (const unsigned long long*)Xw;

    if (tid < 1024) { // taper
      int ii = tid >> 5, jj = tid & 31;
      int ad = ii - jj; if (ad < 0) ad = -ad;
      int dist = (ad < 32 - ad) ? ad : (32 - ad);
      double z = (double)dist / 5.0;
      double z2 = z*z, z3 = z2*z, z4 = z3*z, z5 = z4*z;
      double gval;
      if (z < 1.0) gval = 1.0 - (5.0/3.0)*z2 + (5.0/8.0)*z3 + 0.5*z4 - 0.25*z5;
      else if (z < 2.0) gval = 4.0 - 5.0*z + (5.0/3.0)*z2 + (5.0/8.0)*z3 - 0.5*z4 + (1.0/12.0)*z5 - 2.0/(3.0*z);
      else gval = 0.0;
      taperS[tid] = (float)gval;
    }
    if (tid < 32) { rnS[tid] = rn[tid]; rsdS[tid] = sqrtf(rn[tid]); }
    if (tid < 384) { // mers for all t
      int tt = tid >> 3, jq = tid & 7;
      float sx = 0.f, sy = 0.f, sz = 0.f, sw = 0.f;
      for (int n = 0; n < 128; n++) {
        float4 e = er4[((tt*8+b)*128+n)*8 + jq];
        sx += e.x; sy += e.y; sz += e.z; sw += e.w;
      }
      int o = tt*32 + jq*4;
      mersS[o]   = sx*(1.f/128.f);
      mersS[o+1] = sy*(1.f/128.f);
      mersS[o+2] = sz*(1.f/128.f);
      mersS[o+3] = sw*(1.f/128.f);
    }
    __syncthreads();

    float llacc = 0.f;
    const int i = tid >> 5, j = tid & 31;
    for (int t = 0; t < 48; t++) {
      float yv = 0.f;
      if (tid < 32) yv = y[(b*48+t)*32 + tid];   // prefetch
      if (t > 0) { if (tid < 32) pollge(cnt + tid*16, t); }
      __syncthreads();
      { // load Xw; shuffle row mean; center; write XN
        unsigned long long u0 = aloadu(Xw_u + (i*8+b)*64 + j);
        unsigned long long u1 = aloadu(Xw_u + (i*8+b)*64 + j + 32);
        float2 f0 = __builtin_bit_cast(float2, u0);
        float2 f1 = __builtin_bit_cast(float2, u1);
        float s4 = (f0.x+f0.y)+(f1.x+f1.y);
#pragma unroll
        for (int mk = 1; mk <= 16; mk <<= 1) s4 += __shfl_xor(s4, mk, 64);
        float mu = s4 * (1.f/128.f);
        if (j == 0) XmsS[i] = mu;
        XN[(2*j)*33+i]    = f0.x - mu;
        XN[(2*j+1)*33+i]  = f0.y - mu;
        XN[(2*j+64)*33+i] = f1.x - mu;
        XN[(2*j+65)*33+i] = f1.y - mu;
      }
      __syncthreads();
      float val;
      { // P[i][j] conflict-free (broadcast + consecutive)
        float a0 = 0.f, a1 = 0.f;
#pragma unroll 4
        for (int n = 0; n < 128; n += 2) {
          a0 = fmaf(XN[n*33+i],     XN[n*33+j],     a0);
          a1 = fmaf(XN[(n+1)*33+i], XN[(n+1)*33+j], a1);
        }
        float pv = taperS[i*32+j] * (a0+a1) * (1.f/127.f);
        Ps[i*36+j] = pv;
        val = pv + ((i==j) ? rnS[i] : 0.f);
      }
      // 2x2-pivot block sweep of S in registers -> val = (-Sinv)[i][j]
#pragma unroll 1
      for (int kb = 0; kb < 16; kb++) {
        int k0 = kb*2, k1 = k0+1, par = (kb&1)*72;
        if (i == k0) rowP[par + j]      = val;
        if (i == k1) rowP[par + 36 + j] = val;
        if (j == k0) colP[par + i]      = val;
        if (j == k1) colP[par + 36 + i] = val;
        __syncthreads();
        float a  = rowP[par + k0];
        float bb = rowP[par + k1];
        float c  = rowP[par + 36 + k1];
        float det = fmaf(a, c, -bb*bb);
        float idet = 1.0f/det;
        float ci0 = colP[par + i], ci1 = colP[par + 36 + i];
        float r0j = rowP[par + j], r1j = rowP[par + 36 + j];
        float w0 = (ci0*c - ci1*bb)*idet;
        float w1 = (ci1*a - ci0*bb)*idet;
        float v0 = (c*r0j - bb*r1j)*idet;
        float v1 = (a*r1j - bb*r0j)*idet;
        float nv = val - w0*r0j - w1*r1j;
        if (i == k0) nv = v0;
        if (i == k1) nv = v1;
        if (j == k0) nv = w0;
        if (j == k1) nv = w1;
        if (i == k0 && j == k0) nv = -c*idet;
        if (i == k0 && j == k1) nv =  bb*idet;
        if (i == k1 && j == k0) nv =  bb*idet;
        if (i == k1 && j == k1) nv = -a*idet;
        val = nv;
        if (tid == 0) detS[kb] = det;
      }
      Sinvs[i*33+j] = -val;
      if (tid < 32) {
        float rs = yv - XmsS[tid];
        residS[tid] = rs;
        miS[tid] = fmaf(mersS[t*32+tid], rsdS[tid], rs);
      }
      __syncthreads();
      if (tid < 32) {
        // beta = Sinv@mi; xmp = Xms + mi - rn*beta ; var = rn - rn^2*Sinv_ii  (H = I)
        float bt = 0.f;
#pragma unroll
        for (int k = 0; k < 32; k++) bt = fmaf(Sinvs[tid*33+k], miS[k], bt);
        float xmp = XmsS[tid] + miS[tid] - rnS[tid]*bt;
        out[OFM + (b*48+t)*32 + tid] = xmp;
        out[OFV + (b*48+t)*32 + tid] = rnS[tid] - rnS[tid]*rnS[tid]*Sinvs[tid*33+tid];
        astoref(xm + b*32 + tid, xmp);
      } else if (tid < 64) {
        int ii = tid - 32;
        float al = 0.f;
#pragma unroll
        for (int k = 0; k < 32; k++) al = fmaf(Sinvs[ii*33+k], residS[k], al);
        float contrib = al * residS[ii] + ((ii < 16) ? logf(detS[ii]) : 0.f);
#pragma unroll
        for (int mk = 1; mk <= 16; mk <<= 1) contrib += __shfl_xor(contrib, mk, 64);
        if (ii == 0) {
          llacc += -0.5f*(32.f*LOG2PIF + contrib);
          if (t == 47) astoref(llb + b, llacc);
        }
      }
      gsignal(cnt + (32+b)*16, t+1, tid);
    }
    if (tid < 8) pollge(cnt + (32+tid)*16, 48);
    __syncthreads();
  }

  // ---------------- epilogue: x_final broadcast + elbo ----------------
  if (tid < 128) {
    unsigned long long u = aloadu((const unsigned long long*)xm + tid);
    float2 f = __builtin_bit_cast(float2, u);
    sm[2*tid] = f.x; sm[2*tid+1] = f.y;
  }
  __syncthreads();
  for (int v = blk*1024 + tid; v < 1048576; v += 40960)
    out[1 + v] = sm[v & 255];
  if (blk == 32 && tid == 0) {
    double ll = 0.0;
    for (int i2 = 0; i2 < 8; i2++) ll += (double)aloadf(llb + i2);
    double ldK = 0.0, tr = 0.0, mah = 0.0, ldS = 0.0;
    for (int d2 = 0; d2 < 32; d2++) {
      ldK += (double)kld[d2];
      tr  += (double)kld[32+d2];
      mah += (double)kld[64+d2];
      ldS += (double)kld[96+d2];
    }
    double klv = 0.5*(tr + mah - 4096.0 + 2.0*ldK - 2.0*ldS);
    out[0] = (float)(ll - klv/100000.0);
  }
}

extern "C" void kernel_launch(void* const* d_in, const int* in_sizes, int n_in,
                              void* d_out, int out_size, void* d_ws, size_t ws_size,
                              hipStream_t stream) {
  const float* ips = (const float*)d_in[0];
  const float* ls  = (const float*)d_in[2];
  const float* osc = (const float*)d_in[3];
  const float* qmu = (const float*)d_in[4];
  const float* qL  = (const float*)d_in[5];
  const float* qn  = (const float*)d_in[6];
  const float* rn  = (const float*)d_in[7];
  const float* x0  = (const float*)d_in[8];
  const float* y   = (const float*)d_in[9];
  const float* eu  = (const float*)d_in[10];
  const float* ef  = (const float*)d_in[11];
  const float* eq  = (const float*)d_in[12];
  const float* er  = (const float*)d_in[13];
  float* out = (float*)d_out;
  float* ws  = (float*)d_ws;

  float* w_zsm  = ws + WZSM;
  float* w_zs2  = ws + WZS2;
  float* w_kinv = ws + WKINV;
  float* w_A    = ws + WA;
  float* w_Xw   = ws + WXW;
  float* w_xm   = ws + WXM;
  float* w_llb  = ws + WLLB;
  float* w_kld  = ws + WKLD;
  int*   w_cnt  = (int*)(ws + WCNT);

  k_sweep<<<32, 1024, 0, stream>>>(ips, ls, osc, qL, qmu, w_zsm, w_zs2, w_kinv, w_kld, w_cnt);
  k_UA<<<128, 256, 0, stream>>>(qL, qmu, eu, w_kinv, w_A);
  k_t0gp<<<4096, 128, 0, stream>>>(x0, ls, osc, qn, w_zsm, w_zs2, w_kinv, w_A, ef, eq, w_Xw);
  void* args[] = { (void*)&ls, (void*)&osc, (void*)&qn, (void*)&rn, (void*)&y,
                   (void*)&ef, (void*)&eq, (void*)&er, (void*)&w_zsm, (void*)&w_zs2,
                   (void*)&w_kinv, (void*)&w_A, (void*)&w_Xw, (void*)&w_xm, (void*)&w_llb,
                   (void*)&w_kld, (void*)&out, (void*)&w_cnt };
  hipLaunchCooperativeKernel((void*)k_scan, dim3(40), dim3(1024), args, 0, stream);
}